// Round 1
// baseline (529.783 us; speedup 1.0000x reference)
//
#include <hip/hip_runtime.h>

// UpsampleLayer2D: out[b, r + (k>=2)*R, c + (k&1)*C, co] = x[b, r, c, 4*co + k]
// B=32, R=C=200, Cin=64, Co=16. Pure rearrange, HBM-bound.
//
// Thread g handles input float4 #g (pixel pix = g>>4, vec v = g&15).
// That float4's components are exactly output channel co=v of the 4 output
// quadrant pixels. Loads: perfectly linear float4 stream. Stores: 4 scalar
// stores, each coalesced to contiguous 256B runs across the wave.

#define BATCH 32
#define RWS 200
#define CLS 200
#define CO 16

__global__ __launch_bounds__(256) void upsample2d_kernel(
    const float4* __restrict__ x, float* __restrict__ out, unsigned total) {
    const unsigned stride = gridDim.x * blockDim.x;
    for (unsigned g = blockIdx.x * blockDim.x + threadIdx.x; g < total; g += stride) {
        float4 f = x[g];                       // x[b,r,c, 4v..4v+3] -- linear, coalesced
        unsigned v   = g & 15u;
        unsigned pix = g >> 4;                 // b*R*C + r*C + c
        unsigned b   = pix / (RWS * CLS);
        unsigned rem = pix - b * (RWS * CLS);
        unsigned r   = rem / CLS;
        unsigned c   = rem - r * CLS;
        // output pixel index of quadrant (0,0): row r, col c in [2R, 2C] image
        unsigned o00 = (b * (2u * RWS) + r) * (2u * CLS) + c;
        float* p = out + (size_t)o00 * CO + v;
        p[0]                        = f.x;     // (r,      c)
        p[(size_t)CLS * CO]         = f.y;     // (r,      c+C)
        p[(size_t)(2u*CLS*RWS) * CO]= f.z;     // (r+R,    c)
        p[(size_t)(2u*CLS*RWS + CLS) * CO] = f.w; // (r+R, c+C)
    }
}

extern "C" void kernel_launch(void* const* d_in, const int* in_sizes, int n_in,
                              void* d_out, int out_size, void* d_ws, size_t ws_size,
                              hipStream_t stream) {
    const float4* x = (const float4*)d_in[0];
    float* out = (float*)d_out;
    const unsigned total = (unsigned)BATCH * RWS * CLS * CO;  // 20,480,000 float4-threads
    const int block = 256;
    const int grid = 2048;  // 8 blocks/CU, grid-stride the rest
    upsample2d_kernel<<<grid, block, 0, stream>>>(x, out, total);
}

// Round 2
// 522.264 us; speedup vs baseline: 1.0144x; 1.0144x over previous
//
#include <hip/hip_runtime.h>

// UpsampleLayer2D: out[b, r + (k>=2)*R, c + (k&1)*C, co] = x[b, r, c, 4*co + k]
// B=32, R=C=200, Cin=64, Co=16. Pure rearrange, HBM-bound (~104us roofline).
//
// Thread = (input pixel, quad q in 0..3). Loads input float4s 4q..4q+3 of its
// pixel (64 contiguous bytes), 4x4-transposes in registers, then stores one
// float4 (output channels 4q..4q+3) to each of the 4 output quadrant pixels.
// Each store instruction is a fully contiguous 1KB/wave run (16B/lane).
// Loads: each instr touches 16B of every 64B line; the 4 instrs jointly cover
// every byte -> full line utilization via L1, HBM traffic = 1x input.

#define BATCH 32
#define RWS 200
#define CLS 200

__global__ __launch_bounds__(256) void upsample2d_kernel(
    const float4* __restrict__ x, float4* __restrict__ out, unsigned total) {
    const unsigned stride = gridDim.x * blockDim.x;
    for (unsigned g = blockIdx.x * blockDim.x + threadIdx.x; g < total; g += stride) {
        unsigned q   = g & 3u;
        unsigned pix = g >> 2;                       // b*R*C + r*C + c
        const float4* px = x + (size_t)pix * 16 + q * 4;
        float4 m0 = px[0], m1 = px[1], m2 = px[2], m3 = px[3];

        unsigned b   = pix / (RWS * CLS);
        unsigned rem = pix - b * (RWS * CLS);
        unsigned r   = rem / CLS;
        unsigned c   = rem - r * CLS;
        // output pixel (quadrant 0,0): row r, col c of the [2R,2C] image.
        // As float4 index: each output pixel = 4 float4s; this thread owns #q.
        size_t o00 = ((size_t)(b * 2u * RWS + r) * (2u * CLS) + c) * 4u + q;
        float4* o = out + o00;

        o[0]                               = make_float4(m0.x, m1.x, m2.x, m3.x); // (r,   c)
        o[(size_t)CLS * 4u]                = make_float4(m0.y, m1.y, m2.y, m3.y); // (r,   c+C)
        o[(size_t)(2u*CLS*RWS) * 4u]       = make_float4(m0.z, m1.z, m2.z, m3.z); // (r+R, c)
        o[(size_t)(2u*CLS*RWS + CLS) * 4u] = make_float4(m0.w, m1.w, m2.w, m3.w); // (r+R, c+C)
    }
}

extern "C" void kernel_launch(void* const* d_in, const int* in_sizes, int n_in,
                              void* d_out, int out_size, void* d_ws, size_t ws_size,
                              hipStream_t stream) {
    const float4* x = (const float4*)d_in[0];
    float4* out = (float4*)d_out;
    const unsigned total = (unsigned)BATCH * RWS * CLS * 4u;  // 5,120,000 threads
    const int block = 256;
    const int grid = 2048;  // 8 blocks/CU, grid-stride (10 iters/thread)
    upsample2d_kernel<<<grid, block, 0, stream>>>(x, out, total);
}